// Round 15
// baseline (151.401 us; speedup 1.0000x reference)
//
#include <hip/hip_runtime.h>
#include <hip/hip_bf16.h>

typedef __attribute__((ext_vector_type(8))) short bf16x8;
typedef __attribute__((ext_vector_type(4))) float f32x4;
typedef __attribute__((ext_vector_type(4))) unsigned u32x4;
typedef __attribute__((ext_vector_type(2))) unsigned u32x2;

#define T_LEN 2048
#define S_ENC 256
#define QSCALE 0.18033688011112042f     // 64^-0.5 * log2(e): softmax in log2 domain
#define BARRIER() __syncthreads()

__device__ __forceinline__ float exp2_hw(float x) {
#if __has_builtin(__builtin_amdgcn_exp2f)
  return __builtin_amdgcn_exp2f(x);
#else
  float r;
  asm("v_exp_f32 %0, %1" : "=v"(r) : "v"(x));
  return r;
#endif
}

// hardware packed f32->bf16 (RNE), 2 values per instruction
__device__ __forceinline__ unsigned cvt_pk_bf16(float lo, float hi) {
  unsigned r;
  asm("v_cvt_pk_bf16_f32 %0, %1, %2" : "=v"(r) : "v"(lo), "v"(hi));
  return r;
}

__device__ __forceinline__ short f2bf(float x) {   // cold path (Q frag) only
  union { __hip_bfloat16 b; short s; } u;
  u.b = __float2bfloat16(x);
  return u.s;
}

// XOR bank swizzle (T2, verified: conflicts 9.4M -> 0): rows of 64 shorts
// (128B), 16B-slot index ^= row&7. Applied on BOTH write and read sides.
__device__ __forceinline__ int swz(int row, int col) {
  return row * 64 + (col ^ ((row & 7) << 3));
}

union PU { u32x4 u; bf16x8 b; };

// ---- staging (R9-verbatim index math, htid in 0..255) ----
template<int STRIDE>
__device__ __forceinline__ void issue_loads(
    const float* __restrict__ kb, const float* __restrict__ vb, int s0, int htid,
    float (&kr)[8], float (&kr2)[8], f32x4 (&vr)[4]) {
  const int ks = htid & 63;
  const int kc = (htid >> 6) * 8;
  const float* kp = kb + (size_t)kc * STRIDE + (s0 + ks);
  const float* kp2 = kp + (size_t)32 * STRIDE;
#pragma unroll
  for (int r = 0; r < 8; ++r) kr[r] = kp[(size_t)r * STRIDE];
#pragma unroll
  for (int r = 0; r < 8; ++r) kr2[r] = kp2[(size_t)r * STRIDE];
  const int vg = htid & 15;
  const int vc = htid >> 4;
  const float* vp0 = vb + (size_t)vc * STRIDE + (s0 + 4 * vg);
  vr[0] = *(const f32x4*)(vp0);
  vr[1] = *(const f32x4*)(vp0 + (size_t)32 * STRIDE);
  vr[2] = *(const f32x4*)(vp0 + (size_t)16 * STRIDE);
  vr[3] = *(const f32x4*)(vp0 + (size_t)48 * STRIDE);
}

__device__ __forceinline__ void stage_write(
    short* __restrict__ Kt, short* __restrict__ Vt, int htid,
    const float (&kr)[8], const float (&kr2)[8], const f32x4 (&vr)[4]) {
  const int ks = htid & 63;
  const int kc = (htid >> 6) * 8;
  u32x4 kw;
#pragma unroll
  for (int r = 0; r < 4; ++r) kw[r] = cvt_pk_bf16(kr[2 * r], kr[2 * r + 1]);
  *(u32x4*)(Kt + swz(ks, kc)) = kw;
  u32x4 kw2;
#pragma unroll
  for (int r = 0; r < 4; ++r) kw2[r] = cvt_pk_bf16(kr2[2 * r], kr2[2 * r + 1]);
  *(u32x4*)(Kt + swz(ks, kc + 32)) = kw2;

  const int vg = htid & 15;
  const int vc = htid >> 4;
  const int vcol = 32 * (vg >> 3) + 8 * (vg & 3) + 4 * ((vg >> 2) & 1);  // sigma-perm
  const int vrow[4] = {vc, vc + 32, vc + 16, vc + 48};
#pragma unroll
  for (int i = 0; i < 4; ++i) {
    u32x2 vw;
    vw[0] = cvt_pk_bf16(vr[i][0], vr[i][1]);
    vw[1] = cvt_pk_bf16(vr[i][2], vr[i][3]);
    *(u32x2*)(Vt + swz(vrow[i], vcol)) = vw;
  }
}

// ---- compute (R9 verbatim): qt=4, K-frags hoisted, softmax in qt-pairs ----
__device__ __forceinline__ void compute_tile(
    const short* __restrict__ Kt, const short* __restrict__ Vt,
    const bf16x8 (&qf)[4][2], f32x4 (&o)[4][4], float (&lp)[4], int lane) {
  const int ln = lane & 15;
  const int lg = lane >> 4;

  bf16x8 kf[4][2];
#pragma unroll
  for (int mt = 0; mt < 4; ++mt) {
    const int row = 16 * mt + ln;
    kf[mt][0] = *(const bf16x8*)(Kt + swz(row, 8 * lg));
    kf[mt][1] = *(const bf16x8*)(Kt + swz(row, 32 + 8 * lg));
  }

  PU pfrag[4][2];
#pragma unroll
  for (int pr = 0; pr < 2; ++pr) {
    f32x4 sacc[2][4];
#pragma unroll
    for (int q2 = 0; q2 < 2; ++q2)
#pragma unroll
      for (int mt = 0; mt < 4; ++mt) sacc[q2][mt] = (f32x4){0.f, 0.f, 0.f, 0.f};

#pragma unroll
    for (int mt = 0; mt < 4; ++mt)
#pragma unroll
      for (int q2 = 0; q2 < 2; ++q2) {
        const int qt = 2 * pr + q2;
        sacc[q2][mt] = __builtin_amdgcn_mfma_f32_16x16x32_bf16(kf[mt][0], qf[qt][0], sacc[q2][mt], 0, 0, 0);
        sacc[q2][mt] = __builtin_amdgcn_mfma_f32_16x16x32_bf16(kf[mt][1], qf[qt][1], sacc[q2][mt], 0, 0, 0);
      }

#pragma unroll
    for (int q2 = 0; q2 < 2; ++q2) {
      const int qt = 2 * pr + q2;
      float pmt[4];
#pragma unroll
      for (int mt = 0; mt < 4; ++mt) {
        float p0 = exp2_hw(sacc[q2][mt][0]);
        float p1 = exp2_hw(sacc[q2][mt][1]);
        float p2 = exp2_hw(sacc[q2][mt][2]);
        float p3 = exp2_hw(sacc[q2][mt][3]);
        pfrag[qt][mt >> 1].u[2 * (mt & 1) + 0] = cvt_pk_bf16(p0, p1);
        pfrag[qt][mt >> 1].u[2 * (mt & 1) + 1] = cvt_pk_bf16(p2, p3);
        pmt[mt] = (p0 + p1) + (p2 + p3);
      }
      lp[qt] += (pmt[0] + pmt[1]) + (pmt[2] + pmt[3]);
    }
  }

#pragma unroll
  for (int sub = 0; sub < 2; ++sub)
#pragma unroll
    for (int ct = 0; ct < 4; ++ct) {
      const bf16x8 vf = *(const bf16x8*)(Vt + swz(16 * ct + ln, 32 * sub + 8 * lg));
#pragma unroll
      for (int qt = 0; qt < 4; ++qt)
        o[qt][ct] = __builtin_amdgcn_mfma_f32_16x16x32_bf16(vf, pfrag[qt][sub].b, o[qt][ct], 0, 0, 0);
    }
}

// 512 threads = 8 waves. Waves 0-3: key-half 0; waves 4-7: key-half 1.
// Same 256 queries per block; partial (O,l) combined in LDS at the end
// (no-max log2 softmax => partials are plain sums).
__global__ __launch_bounds__(512, 3) void attn_kernel(
    const float* __restrict__ qkv, const float* __restrict__ ekv,
    float* __restrict__ out) {
  const int tid = threadIdx.x;
  const int lane = tid & 63;
  const int wave = tid >> 6;              // 0..7
  const int w = wave & 3;                 // query sub-block
  const int khalf = wave >> 2;            // key half
  const int htid = tid & 255;             // staging id within half
  const int ln = lane & 15;
  const int lg = lane >> 4;

  // XCD swizzle (verified): all 8 q-blocks of one head on the same XCD
  const int bh = blockIdx.x & 63;
  const int qb = blockIdx.x >> 6;         // 0..7
  const int t0 = qb * 256 + w * 64;       // this wave: queries t0 .. t0+63

  const float* qp  = qkv + (size_t)bh * 192 * T_LEN;
  const float* kp  = qp + (size_t)64 * T_LEN + khalf * 1024;
  const float* vp  = qp + (size_t)128 * T_LEN + khalf * 1024;
  const float* ekp = ekv + (size_t)bh * 128 * S_ENC + khalf * 128;
  const float* evp = ekp + (size_t)64 * S_ENC;

  // 32 KB: per-half K (8 KB) + V (8 KB); reused as f32x4 buffer in combine
  __shared__ __attribute__((aligned(16))) short smem[16384];
  __shared__ float lbuf[4][4][16];
  short* Kt = smem + khalf * 4096;
  short* Vt = smem + 8192 + khalf * 4096;

  // Q fragments (channel mapping 32*kk + 8*lg + j, matching K-frag reads)
  bf16x8 qf[4][2];
#pragma unroll
  for (int qt = 0; qt < 4; ++qt)
#pragma unroll
    for (int kk = 0; kk < 2; ++kk)
#pragma unroll
      for (int j = 0; j < 8; ++j)
        qf[qt][kk][j] =
            f2bf(qp[(size_t)(32 * kk + 8 * lg + j) * T_LEN + (t0 + 16 * qt + ln)] * QSCALE);

  f32x4 o[4][4];
#pragma unroll
  for (int qt = 0; qt < 4; ++qt)
#pragma unroll
    for (int ct = 0; ct < 4; ++ct) o[qt][ct] = (f32x4){0.f, 0.f, 0.f, 0.f};
  float lp[4] = {0.f, 0.f, 0.f, 0.f};

  // ---- main loop: 18 tiles per half (2 encoder + 16 self), R9 structure ----
  for (int st = 0; st < 2; ++st) {
    float kr[8], kr2[8];
    f32x4 vr[4];
    issue_loads<S_ENC>(ekp, evp, 64 * st, htid, kr, kr2, vr);
    BARRIER();
    stage_write(Kt, Vt, htid, kr, kr2, vr);
    BARRIER();
    compute_tile(Kt, Vt, qf, o, lp, lane);
  }
  for (int st = 0; st < 16; ++st) {
    float kr[8], kr2[8];
    f32x4 vr[4];
    issue_loads<T_LEN>(kp, vp, 64 * st, htid, kr, kr2, vr);
    BARRIER();
    stage_write(Kt, Vt, htid, kr, kr2, vr);
    BARRIER();
    compute_tile(Kt, Vt, qf, o, lp, lane);
  }

  // ---- combine halves ----
  // l: reduce across lane groups, then exchange half0 -> half1
  float lsum[4];
#pragma unroll
  for (int qt = 0; qt < 4; ++qt) {
    float l = lp[qt];
    l += __shfl_xor(l, 16);
    l += __shfl_xor(l, 32);
    lsum[qt] = l;
  }
  BARRIER();   // all waves done with K/V LDS reads
  if (khalf == 0 && lg == 0) {
#pragma unroll
    for (int qt = 0; qt < 4; ++qt) lbuf[w][qt][ln] = lsum[qt];
  }
  BARRIER();
  float inv[4];
  if (khalf == 1) {
#pragma unroll
    for (int qt = 0; qt < 4; ++qt) inv[qt] = 1.0f / (lsum[qt] + lbuf[w][qt][ln]);
  }

  // O: 2 chunks of 2 q-subtiles (each chunk = 32 KB, reuses smem)
  f32x4* fbuf = (f32x4*)smem;
  for (int c = 0; c < 2; ++c) {
    if (khalf == 0) {
#pragma unroll
      for (int qtl = 0; qtl < 2; ++qtl)
#pragma unroll
        for (int ct = 0; ct < 4; ++ct)
          fbuf[(((w * 2 + qtl) * 4 + ct) * 4 + lg) * 16 + ln] = o[2 * c + qtl][ct];
    }
    BARRIER();
    if (khalf == 1) {
#pragma unroll
      for (int qtl = 0; qtl < 2; ++qtl) {
        const int qt = 2 * c + qtl;
        float* ob = out + (size_t)bh * 64 * T_LEN + (t0 + 16 * qt + ln);
#pragma unroll
        for (int ct = 0; ct < 4; ++ct) {
          const f32x4 t = fbuf[(((w * 2 + qtl) * 4 + ct) * 4 + lg) * 16 + ln];
#pragma unroll
          for (int r = 0; r < 4; ++r)
            ob[(size_t)(16 * ct + 4 * lg + r) * T_LEN] = (o[qt][ct][r] + t[r]) * inv[qt];
        }
      }
    }
    BARRIER();
  }
}

extern "C" void kernel_launch(void* const* d_in, const int* in_sizes, int n_in,
                              void* d_out, int out_size, void* d_ws, size_t ws_size,
                              hipStream_t stream) {
  const float* qkv = (const float*)d_in[0];
  const float* ekv = (const float*)d_in[1];
  float* out = (float*)d_out;
  attn_kernel<<<dim3(512), dim3(512), 0, stream>>>(qkv, ekv, out);
}